// Round 1
// baseline (415.504 us; speedup 1.0000x reference)
//
#include <hip/hip_runtime.h>
#include <cstdint>

#define TSEQ 4096
#define DIMD 1024
#define NBATCH 4
#define MTOT (NBATCH*TSEQ)   // 16384 rows total
#define NSUB 9               // band subtiles of 64 => covers s-t up to >=511
#define PW (NSUB*64)         // 576 stored band width

typedef __bf16 bf16;
typedef bf16 bf16x8 __attribute__((ext_vector_type(8)));
typedef bf16 bf16x4 __attribute__((ext_vector_type(4)));
typedef float f32x4 __attribute__((ext_vector_type(4)));

__device__ __forceinline__ void gl2lds16(const void* g, void* l) {
  // async global->LDS, 16B per lane; LDS dest is wave-uniform base + lane*16
  __builtin_amdgcn_global_load_lds(
      (__attribute__((address_space(1))) void*)(g),
      (__attribute__((address_space(3))) void*)(l), 16, 0, 0);
}
__device__ __forceinline__ f32x4 mfma16(bf16x8 a, bf16x8 b, f32x4 c) {
  return __builtin_amdgcn_mfma_f32_16x16x32_bf16(a, b, c, 0, 0, 0);
}

// ---------------- fp32 -> bf16 convert ----------------
__global__ void cvt_kernel(const float* __restrict__ in, bf16* __restrict__ out, int n) {
  int i = (blockIdx.x * 256 + threadIdx.x) * 4;
  if (i >= n) return;
  float4 v = *(const float4*)(in + i);
  bf16x4 o = { (bf16)v.x, (bf16)v.y, (bf16)v.z, (bf16)v.w };
  *(bf16x4*)(out + i) = o;
}

// ---------------- C = A @ B^T  (A[M,K], B[N,K] both row-major bf16) ----------------
// 128x128 tile, 4 waves 2x2, each wave 4x4 16x16x32 MFMAs per K-chunk of 32.
__global__ void gemm_bt(const bf16* __restrict__ A, const bf16* __restrict__ B,
                        bf16* __restrict__ Cb, float* __restrict__ Cf,
                        const float* __restrict__ scale_ptr, int N, int K) {
  __shared__ bf16 As[128*32];
  __shared__ bf16 Bs[128*32];
  const int tid = threadIdx.x;
  const int wave = tid >> 6, lane = tid & 63;
  const int row0 = blockIdx.x * 128, col0 = blockIdx.y * 128;
  const int wr = wave >> 1, wc = wave & 1;
  f32x4 acc[4][4] = {};
  // staging: wave covers 32 rows (2 issues of 16); lane -> row l>>2, kchunk (l&3)*8
  const int srow = wave*32 + (lane>>2);
  const int scol = (lane&3)*8;
  const bf16* gA = A + (size_t)(row0 + srow)*K + scol;
  const bf16* gB = B + (size_t)(col0 + srow)*K + scol;
  bf16* lA = As + (wave*32)*32;
  bf16* lB = Bs + (wave*32)*32;
  for (int k0 = 0; k0 < K; k0 += 32) {
    gl2lds16(gA,               lA);
    gl2lds16(gA + (size_t)16*K, lA + 16*32);
    gl2lds16(gB,               lB);
    gl2lds16(gB + (size_t)16*K, lB + 16*32);
    gA += 32; gB += 32;
    __syncthreads();
    bf16x8 af[4], bfr[4];
    #pragma unroll
    for (int i = 0; i < 4; ++i) {
      af[i]  = *(const bf16x8*)(As + (wr*64 + i*16 + (lane&15))*32 + (lane>>4)*8);
      bfr[i] = *(const bf16x8*)(Bs + (wc*64 + i*16 + (lane&15))*32 + (lane>>4)*8);
    }
    #pragma unroll
    for (int i = 0; i < 4; ++i)
      #pragma unroll
      for (int j = 0; j < 4; ++j)
        acc[i][j] = mfma16(af[i], bfr[j], acc[i][j]);
    __syncthreads();
  }
  float sc = scale_ptr ? *scale_ptr : 1.0f;
  #pragma unroll
  for (int i = 0; i < 4; ++i) {
    #pragma unroll
    for (int j = 0; j < 4; ++j) {
      int col  = col0 + wc*64 + j*16 + (lane&15);
      int rowb = row0 + wr*64 + i*16 + (lane>>4)*4;
      #pragma unroll
      for (int r = 0; r < 4; ++r) {
        float v = acc[i][j][r] * sc;
        if (Cf) Cf[(size_t)(rowb + r)*N + col] = v;
        else    Cb[(size_t)(rowb + r)*N + col] = (bf16)v;
      }
    }
  }
}

// ---------------- V[b][T][D] -> Vt[b][D][T] ----------------
__global__ void transpose_kernel(const bf16* __restrict__ V, bf16* __restrict__ Vt) {
  __shared__ bf16 tile[64][72];   // +8 pad: rows stay 16B-aligned, breaks bank stride
  int b = blockIdx.z;
  int t0 = blockIdx.x * 64, c0 = blockIdx.y * 64;
  int tid = threadIdx.x;
  int r = tid >> 2, cb = (tid & 3) * 16;
  const bf16* src = V + ((size_t)b*TSEQ + t0 + r)*DIMD + c0 + cb;
  *(bf16x8*)&tile[r][cb]     = *(const bf16x8*)src;
  *(bf16x8*)&tile[r][cb + 8] = *(const bf16x8*)(src + 8);
  __syncthreads();
  int cr = tid >> 2, tb = (tid & 3) * 16;
  bf16x8 o0, o1;
  #pragma unroll
  for (int j = 0; j < 8; ++j) { o0[j] = tile[tb+j][cr]; o1[j] = tile[tb+8+j][cr]; }
  bf16* dst = Vt + ((size_t)b*DIMD + c0 + cr)*TSEQ + t0 + tb;
  *(bf16x8*)dst       = o0;
  *(bf16x8*)(dst + 8) = o1;
}

// ---------------- banded weighted scores: P[b][qt][i][st*64+j] ----------------
// block: one (qt, st) 64x64 tile of S = Q K^T; epilogue applies scale * decay weight.
__global__ void score_kernel(const bf16* __restrict__ Q, const bf16* __restrict__ Kmat,
                             bf16* __restrict__ P, const float* __restrict__ dlogit) {
  __shared__ bf16 Qs[64*32];
  __shared__ bf16 Ks[64*32];
  int st = blockIdx.x, qt = blockIdx.y, b = blockIdx.z;
  int i0 = qt*64, s0 = i0 + st*64;
  int tid = threadIdx.x, wave = tid>>6, lane = tid&63;
  f32x4 acc[4] = {};
  int r = wave*16 + (lane>>2), c = (lane&3)*8;
  const bf16* gq = Q + ((size_t)b*TSEQ + i0 + r)*DIMD + c;
  int sr = s0 + r; if (sr > TSEQ-1) sr = TSEQ-1;   // clamp OOB rows; weight=0 masks them
  const bf16* gk = Kmat + ((size_t)b*TSEQ + sr)*DIMD + c;
  bf16* lq = Qs + (wave*16)*32;
  bf16* lk = Ks + (wave*16)*32;
  for (int k0 = 0; k0 < DIMD; k0 += 32) {
    gl2lds16(gq, lq); gq += 32;
    gl2lds16(gk, lk); gk += 32;
    __syncthreads();
    bf16x8 qf = *(const bf16x8*)(Qs + (wave*16 + (lane&15))*32 + (lane>>4)*8);
    #pragma unroll
    for (int j = 0; j < 4; ++j) {
      bf16x8 kf = *(const bf16x8*)(Ks + (j*16 + (lane&15))*32 + (lane>>4)*8);
      acc[j] = mfma16(qf, kf, acc[j]);
    }
    __syncthreads();
  }
  float decay = 1.0f / (1.0f + expf(-*dlogit));
  float l2d = log2f(decay);
  bf16* Pp = P + ((size_t)b*(TSEQ/64) + qt)*64*PW;
  #pragma unroll
  for (int j = 0; j < 4; ++j) {
    int jj = j*16 + (lane&15);
    int s = s0 + jj;
    #pragma unroll
    for (int rr = 0; rr < 4; ++rr) {
      int i = wave*16 + (lane>>4)*4 + rr;
      int t = i0 + i;
      float w = (s > t && s < TSEQ) ? exp2f((float)(s - t - 1) * l2d) : 0.0f;
      Pp[(size_t)i*PW + st*64 + jj] = (bf16)(acc[j][rr] * 0.03125f * w);
    }
  }
}

// ---------------- R[64 x 128 tile] = P_band @ V  (B operand from Vt) ----------------
__global__ void pv_kernel(const bf16* __restrict__ P, const bf16* __restrict__ Vt,
                          bf16* __restrict__ R) {
  __shared__ bf16 Ps[64*64];
  __shared__ bf16 Vs[128*64];
  int cb = blockIdx.x, qt = blockIdx.y, b = blockIdx.z;
  int i0 = qt*64, c0 = cb*128;
  int tid = threadIdx.x, wave = tid>>6, lane = tid&63;
  int wr = wave>>1, wc = wave&1;
  f32x4 acc[2][4] = {};
  const bf16* Pp = P + ((size_t)b*(TSEQ/64) + qt)*64*PW;
  for (int st = 0; st < NSUB; ++st) {
    int s0 = i0 + st*64;
    #pragma unroll
    for (int is = 0; is < 2; ++is) {
      int rr = wave*16 + is*8 + (lane>>3);
      int cc = (lane&7)*8;
      gl2lds16(Pp + (size_t)rr*PW + st*64 + cc, Ps + (wave*16 + is*8)*64);
    }
    #pragma unroll
    for (int is = 0; is < 4; ++is) {
      int rr = wave*32 + is*8 + (lane>>3);       // c row within 128
      int si = s0 + (lane&7)*8;
      if (si > TSEQ-8) si = TSEQ-8;              // keep reads in-bounds; P=0 masks
      gl2lds16(Vt + ((size_t)b*DIMD + c0 + rr)*TSEQ + si, Vs + (wave*32 + is*8)*64);
    }
    __syncthreads();
    #pragma unroll
    for (int kc = 0; kc < 2; ++kc) {
      bf16x8 af[2], bfr[4];
      #pragma unroll
      for (int i = 0; i < 2; ++i)
        af[i] = *(const bf16x8*)(Ps + (wr*32 + i*16 + (lane&15))*64 + kc*32 + (lane>>4)*8);
      #pragma unroll
      for (int j = 0; j < 4; ++j)
        bfr[j] = *(const bf16x8*)(Vs + (wc*64 + j*16 + (lane&15))*64 + kc*32 + (lane>>4)*8);
      #pragma unroll
      for (int i = 0; i < 2; ++i)
        #pragma unroll
        for (int j = 0; j < 4; ++j)
          acc[i][j] = mfma16(af[i], bfr[j], acc[i][j]);
    }
    __syncthreads();
  }
  #pragma unroll
  for (int i = 0; i < 2; ++i)
    #pragma unroll
    for (int j = 0; j < 4; ++j) {
      int col  = c0 + wc*64 + j*16 + (lane&15);
      int rowb = i0 + wr*32 + i*16 + (lane>>4)*4;
      #pragma unroll
      for (int rr = 0; rr < 4; ++rr)
        R[((size_t)b*TSEQ + rowb + rr)*DIMD + col] = (bf16)acc[i][j][rr];
    }
}

extern "C" void kernel_launch(void* const* d_in, const int* in_sizes, int n_in,
                              void* d_out, int out_size, void* d_ws, size_t ws_size,
                              hipStream_t stream) {
  const float* x      = (const float*)d_in[0];
  const float* Wq     = (const float*)d_in[1];
  const float* Wk     = (const float*)d_in[2];
  const float* Wv     = (const float*)d_in[3];
  const float* Wo     = (const float*)d_in[4];
  const float* dlogit = (const float*)d_in[5];
  const float* oscale = (const float*)d_in[6];
  float* out = (float*)d_out;

  char* ws = (char*)d_ws;
  size_t off = 0;
  auto alloc = [&](size_t bytes) -> void* {
    void* p = ws + off; off += (bytes + 255) & ~(size_t)255; return p;
  };
  const size_t XN = (size_t)MTOT * DIMD;           // 16,777,216 elements
  bf16* xb  = (bf16*)alloc(XN * 2);
  bf16* Qb  = (bf16*)alloc(XN * 2);
  bf16* Kb  = (bf16*)alloc(XN * 2);
  bf16* Vb  = (bf16*)alloc(XN * 2);
  bf16* Vtb = (bf16*)alloc(XN * 2);
  bf16* Wqb = (bf16*)alloc((size_t)DIMD*DIMD*2);
  bf16* Wkb = (bf16*)alloc((size_t)DIMD*DIMD*2);
  bf16* Wvb = (bf16*)alloc((size_t)DIMD*DIMD*2);
  bf16* Wob = (bf16*)alloc((size_t)DIMD*DIMD*2);
  if (ws_size < off) return;                       // loud failure if ws too small
  bf16* Rb = xb;   // alias: xb dead after V projection
  bf16* Pb = Vb;   // alias: Vb dead after transpose (P needs 18.9MB <= 32MB)

  // fp32 -> bf16
  cvt_kernel<<<dim3((unsigned)(XN/1024)), dim3(256), 0, stream>>>(x, xb, (int)XN);
  int wn = DIMD*DIMD;
  cvt_kernel<<<dim3(wn/1024), dim3(256), 0, stream>>>(Wq, Wqb, wn);
  cvt_kernel<<<dim3(wn/1024), dim3(256), 0, stream>>>(Wk, Wkb, wn);
  cvt_kernel<<<dim3(wn/1024), dim3(256), 0, stream>>>(Wv, Wvb, wn);
  cvt_kernel<<<dim3(wn/1024), dim3(256), 0, stream>>>(Wo, Wob, wn);

  // projections
  dim3 gg(MTOT/128, DIMD/128);
  gemm_bt<<<gg, dim3(256), 0, stream>>>(xb, Wqb, Qb, nullptr, nullptr, DIMD, DIMD);
  gemm_bt<<<gg, dim3(256), 0, stream>>>(xb, Wkb, Kb, nullptr, nullptr, DIMD, DIMD);
  gemm_bt<<<gg, dim3(256), 0, stream>>>(xb, Wvb, Vb, nullptr, nullptr, DIMD, DIMD);

  // V transpose for PV B-operand
  transpose_kernel<<<dim3(TSEQ/64, DIMD/64, NBATCH), dim3(256), 0, stream>>>(Vb, Vtb);

  // banded weighted scores
  score_kernel<<<dim3(NSUB, TSEQ/64, NBATCH), dim3(256), 0, stream>>>(Qb, Kb, Pb, dlogit);

  // P @ V
  pv_kernel<<<dim3(DIMD/128, TSEQ/64, NBATCH), dim3(256), 0, stream>>>(Pb, Vtb, Rb);

  // output projection with out_scale, fp32 out
  gemm_bt<<<gg, dim3(256), 0, stream>>>(Rb, Wob, nullptr, out, oscale, DIMD, DIMD);
}

// Round 2
// 414.081 us; speedup vs baseline: 1.0034x; 1.0034x over previous
//
#include <hip/hip_runtime.h>
#include <cstdint>

#define TSEQ 4096
#define DIMD 1024
#define NBATCH 4
#define MTOT (NBATCH*TSEQ)   // 16384 rows total
#define NST 5                // band subtiles of 128 => covers s-t up to 639 (decay^638 ~ 4e-14)
#define PW (NST*128)         // 640 stored band width

typedef __bf16 bf16;
typedef bf16 bf16x8 __attribute__((ext_vector_type(8)));
typedef bf16 bf16x4 __attribute__((ext_vector_type(4)));
typedef float f32x4 __attribute__((ext_vector_type(4)));

__device__ __forceinline__ void gl2lds16(const void* g, void* l) {
  // async global->LDS, 16B per lane; LDS dest is wave-uniform base + lane*16
  __builtin_amdgcn_global_load_lds(
      (__attribute__((address_space(1))) void*)(g),
      (__attribute__((address_space(3))) void*)(l), 16, 0, 0);
}
__device__ __forceinline__ f32x4 mfma16(bf16x8 a, bf16x8 b, f32x4 c) {
  return __builtin_amdgcn_mfma_f32_16x16x32_bf16(a, b, c, 0, 0, 0);
}

// ---------------- fp32 -> bf16 convert ----------------
__global__ void cvt_kernel(const float* __restrict__ in, bf16* __restrict__ out, int n) {
  int i = (blockIdx.x * 256 + threadIdx.x) * 4;
  if (i >= n) return;
  float4 v = *(const float4*)(in + i);
  bf16x4 o = { (bf16)v.x, (bf16)v.y, (bf16)v.z, (bf16)v.w };
  *(bf16x4*)(out + i) = o;
}

// 4 sources in one dispatch (weights); blockIdx.y selects the pair.
__global__ void cvt4_kernel(const float* __restrict__ s0, const float* __restrict__ s1,
                            const float* __restrict__ s2, const float* __restrict__ s3,
                            bf16* __restrict__ d0, bf16* __restrict__ d1,
                            bf16* __restrict__ d2, bf16* __restrict__ d3) {
  const float* srcs[4] = {s0, s1, s2, s3};
  bf16*        dsts[4] = {d0, d1, d2, d3};
  const float* in = srcs[blockIdx.y];
  bf16* out = dsts[blockIdx.y];
  int i = (blockIdx.x * 256 + threadIdx.x) * 4;
  float4 v = *(const float4*)(in + i);
  bf16x4 o = { (bf16)v.x, (bf16)v.y, (bf16)v.z, (bf16)v.w };
  *(bf16x4*)(out + i) = o;
}

// ---------------- C = A @ B^T  (A[M,K], B[N,K] both row-major bf16) ----------------
// 128x128 tile, 4 waves 2x2, each wave 4x4 16x16x32 MFMAs per K-chunk of 32.
// split!=0: N is a multiple of 1024 and output goes to Cb + (col>>10)*MTOT*1024
//           with inner stride 1024 (fused QKV projection -> separate Q/K/V buffers).
__global__ void gemm_bt(const bf16* __restrict__ A, const bf16* __restrict__ B,
                        bf16* __restrict__ Cb, float* __restrict__ Cf,
                        const float* __restrict__ scale_ptr, int N, int K, int split) {
  __shared__ bf16 As[128*32];
  __shared__ bf16 Bs[128*32];
  const int tid = threadIdx.x;
  const int wave = tid >> 6, lane = tid & 63;
  const int row0 = blockIdx.x * 128, col0 = blockIdx.y * 128;
  const int wr = wave >> 1, wc = wave & 1;
  f32x4 acc[4][4] = {};
  const int srow = wave*32 + (lane>>2);
  const int scol = (lane&3)*8;
  const bf16* gA = A + (size_t)(row0 + srow)*K + scol;
  const bf16* gB = B + (size_t)(col0 + srow)*K + scol;
  bf16* lA = As + (wave*32)*32;
  bf16* lB = Bs + (wave*32)*32;
  for (int k0 = 0; k0 < K; k0 += 32) {
    gl2lds16(gA,                lA);
    gl2lds16(gA + (size_t)16*K, lA + 16*32);
    gl2lds16(gB,                lB);
    gl2lds16(gB + (size_t)16*K, lB + 16*32);
    gA += 32; gB += 32;
    __syncthreads();
    bf16x8 af[4], bfr[4];
    #pragma unroll
    for (int i = 0; i < 4; ++i) {
      af[i]  = *(const bf16x8*)(As + (wr*64 + i*16 + (lane&15))*32 + (lane>>4)*8);
      bfr[i] = *(const bf16x8*)(Bs + (wc*64 + i*16 + (lane&15))*32 + (lane>>4)*8);
    }
    #pragma unroll
    for (int i = 0; i < 4; ++i)
      #pragma unroll
      for (int j = 0; j < 4; ++j)
        acc[i][j] = mfma16(af[i], bfr[j], acc[i][j]);
    __syncthreads();
  }
  float sc = scale_ptr ? *scale_ptr : 1.0f;
  #pragma unroll
  for (int i = 0; i < 4; ++i) {
    #pragma unroll
    for (int j = 0; j < 4; ++j) {
      int col  = col0 + wc*64 + j*16 + (lane&15);
      int rowb = row0 + wr*64 + i*16 + (lane>>4)*4;
      #pragma unroll
      for (int r = 0; r < 4; ++r) {
        float v = acc[i][j][r] * sc;
        if (split) {
          size_t idx = ((size_t)(col >> 10) * MTOT + (rowb + r)) * 1024 + (col & 1023);
          Cb[idx] = (bf16)v;
        } else if (Cf) {
          Cf[(size_t)(rowb + r)*N + col] = v;
        } else {
          Cb[(size_t)(rowb + r)*N + col] = (bf16)v;
        }
      }
    }
  }
}

// ---------------- V[b][T][D] -> Vt[b][D][T] ----------------
__global__ void transpose_kernel(const bf16* __restrict__ V, bf16* __restrict__ Vt) {
  __shared__ bf16 tile[64][72];   // +8 pad keeps 16B alignment, breaks bank stride
  int b = blockIdx.z;
  int t0 = blockIdx.x * 64, c0 = blockIdx.y * 64;
  int tid = threadIdx.x;
  int r = tid >> 2, cb = (tid & 3) * 16;
  const bf16* src = V + ((size_t)b*TSEQ + t0 + r)*DIMD + c0 + cb;
  *(bf16x8*)&tile[r][cb]     = *(const bf16x8*)src;
  *(bf16x8*)&tile[r][cb + 8] = *(const bf16x8*)(src + 8);
  __syncthreads();
  int cr = tid >> 2, tb = (tid & 3) * 16;
  bf16x8 o0, o1;
  #pragma unroll
  for (int j = 0; j < 8; ++j) { o0[j] = tile[tb+j][cr]; o1[j] = tile[tb+8+j][cr]; }
  bf16* dst = Vt + ((size_t)b*DIMD + c0 + cr)*TSEQ + t0 + tb;
  *(bf16x8*)dst       = o0;
  *(bf16x8*)(dst + 8) = o1;
}

// ---------------- banded weighted scores, 128x128 tiles ----------------
// P[b][qt][row 0..127][j 0..639], j = s - qt*128. One block per (st, qt, b).
__global__ void score_kernel(const bf16* __restrict__ Q, const bf16* __restrict__ Km,
                             bf16* __restrict__ P, const float* __restrict__ dlogit) {
  __shared__ bf16 Qs[128*32];
  __shared__ bf16 Ks[128*32];
  const int st = blockIdx.x, qt = blockIdx.y, b = blockIdx.z;
  const int i0 = qt*128, s0 = i0 + st*128;
  const int tid = threadIdx.x, wave = tid>>6, lane = tid&63;
  const int wr = wave>>1, wc = wave&1;
  bf16* Pp = P + ((size_t)b*(TSEQ/128) + qt)*128*PW;
  if (s0 >= TSEQ) {            // fully out-of-range tile: write zeros (pv reads full band)
    int row = tid >> 1, cb = (tid & 1)*64;
    bf16x8 z = {};
    #pragma unroll
    for (int v = 0; v < 8; ++v)
      *(bf16x8*)(Pp + (size_t)row*PW + st*128 + cb + v*8) = z;
    return;
  }
  f32x4 acc[4][4] = {};
  const int srow = wave*32 + (lane>>2);
  const int scol = (lane&3)*8;
  const bf16* gq = Q + ((size_t)b*TSEQ + i0 + srow)*DIMD + scol;
  int sr1 = s0 + srow;      if (sr1 > TSEQ-1) sr1 = TSEQ-1;   // clamp OOB rows; w=0 masks
  int sr2 = s0 + srow + 16; if (sr2 > TSEQ-1) sr2 = TSEQ-1;
  const bf16* gk1 = Km + ((size_t)b*TSEQ + sr1)*DIMD + scol;
  const bf16* gk2 = Km + ((size_t)b*TSEQ + sr2)*DIMD + scol;
  bf16* lq = Qs + (wave*32)*32;
  bf16* lk = Ks + (wave*32)*32;
  for (int k0 = 0; k0 < DIMD; k0 += 32) {
    gl2lds16(gq,            lq);
    gl2lds16(gq + 16*DIMD,  lq + 16*32);
    gl2lds16(gk1,           lk);
    gl2lds16(gk2,           lk + 16*32);
    gq += 32; gk1 += 32; gk2 += 32;
    __syncthreads();
    bf16x8 af[4], bfr[4];
    #pragma unroll
    for (int i = 0; i < 4; ++i) {
      af[i]  = *(const bf16x8*)(Qs + (wr*64 + i*16 + (lane&15))*32 + (lane>>4)*8);
      bfr[i] = *(const bf16x8*)(Ks + (wc*64 + i*16 + (lane&15))*32 + (lane>>4)*8);
    }
    #pragma unroll
    for (int i = 0; i < 4; ++i)
      #pragma unroll
      for (int j = 0; j < 4; ++j)
        acc[i][j] = mfma16(af[i], bfr[j], acc[i][j]);
    __syncthreads();
  }
  float decay = 1.0f / (1.0f + expf(-*dlogit));
  float l2d = log2f(decay);
  #pragma unroll
  for (int i = 0; i < 4; ++i) {
    #pragma unroll
    for (int j = 0; j < 4; ++j) {
      int col = wc*64 + j*16 + (lane&15);
      int s = s0 + col;
      #pragma unroll
      for (int r = 0; r < 4; ++r) {
        int row = wr*64 + i*16 + (lane>>4)*4 + r;
        int t = i0 + row;
        float w = (s > t && s < TSEQ) ? exp2f((float)(s - t - 1) * l2d) : 0.0f;
        Pp[(size_t)row*PW + st*128 + col] = (bf16)(acc[i][j][r] * 0.03125f * w);
      }
    }
  }
}

// ---------------- R[128x128 tile] = P_band @ V  (B operand from Vt) ----------------
__global__ void pv_kernel(const bf16* __restrict__ P, const bf16* __restrict__ Vt,
                          bf16* __restrict__ R) {
  __shared__ bf16 Ps[128*32];
  __shared__ bf16 Vs[128*32];
  const int cb = blockIdx.x, qt = blockIdx.y, b = blockIdx.z;
  const int i0 = qt*128, c0 = cb*128;
  const int tid = threadIdx.x, wave = tid>>6, lane = tid&63;
  const int wr = wave>>1, wc = wave&1;
  f32x4 acc[4][4] = {};
  const bf16* Pp = P + ((size_t)b*(TSEQ/128) + qt)*128*PW;
  const int srow = wave*32 + (lane>>2);
  const int scol = (lane&3)*8;
  const bf16* gp = Pp + (size_t)srow*PW + scol;
  bf16* lp = Ps + (wave*32)*32;
  bf16* lv = Vs + (wave*32)*32;
  const bf16* vbase1 = Vt + ((size_t)b*DIMD + c0 + srow)*TSEQ;
  const bf16* vbase2 = vbase1 + (size_t)16*TSEQ;
  for (int k0 = 0; k0 < PW; k0 += 32) {
    gl2lds16(gp,           lp);
    gl2lds16(gp + 16*PW,   lp + 16*32);
    int s = i0 + k0 + scol;
    if (s >= TSEQ) s = 0;              // OOB k: P is 0 there, any valid addr works
    gl2lds16(vbase1 + s,   lv);
    gl2lds16(vbase2 + s,   lv + 16*32);
    gp += 32;
    __syncthreads();
    bf16x8 af[4], bfr[4];
    #pragma unroll
    for (int i = 0; i < 4; ++i) {
      af[i]  = *(const bf16x8*)(Ps + (wr*64 + i*16 + (lane&15))*32 + (lane>>4)*8);
      bfr[i] = *(const bf16x8*)(Vs + (wc*64 + i*16 + (lane&15))*32 + (lane>>4)*8);
    }
    #pragma unroll
    for (int i = 0; i < 4; ++i)
      #pragma unroll
      for (int j = 0; j < 4; ++j)
        acc[i][j] = mfma16(af[i], bfr[j], acc[i][j]);
    __syncthreads();
  }
  #pragma unroll
  for (int i = 0; i < 4; ++i)
    #pragma unroll
    for (int j = 0; j < 4; ++j) {
      int col  = c0 + wc*64 + j*16 + (lane&15);
      int rowb = i0 + wr*64 + i*16 + (lane>>4)*4;
      #pragma unroll
      for (int r = 0; r < 4; ++r)
        R[((size_t)b*TSEQ + rowb + r)*DIMD + col] = (bf16)acc[i][j][r];
    }
}

extern "C" void kernel_launch(void* const* d_in, const int* in_sizes, int n_in,
                              void* d_out, int out_size, void* d_ws, size_t ws_size,
                              hipStream_t stream) {
  const float* x      = (const float*)d_in[0];
  const float* Wq     = (const float*)d_in[1];
  const float* Wk     = (const float*)d_in[2];
  const float* Wv     = (const float*)d_in[3];
  const float* Wo     = (const float*)d_in[4];
  const float* dlogit = (const float*)d_in[5];
  const float* oscale = (const float*)d_in[6];
  float* out = (float*)d_out;

  char* ws = (char*)d_ws;
  size_t off = 0;
  auto alloc = [&](size_t bytes) -> void* {
    void* p = ws + off; off += (bytes + 255) & ~(size_t)255; return p;
  };
  const size_t XN = (size_t)MTOT * DIMD;              // 16,777,216 elements
  const size_t WN = (size_t)DIMD * DIMD;
  bf16* xb   = (bf16*)alloc(XN * 2);                  // 32 MB
  bf16* QKVb = (bf16*)alloc(3 * XN * 2);              // 96 MB: Q | K | V
  bf16* Vtb  = (bf16*)alloc(XN * 2);                  // 32 MB
  bf16* Wcat = (bf16*)alloc(3 * WN * 2);              // 6 MB: Wq | Wk | Wv rows
  bf16* Wob  = (bf16*)alloc(WN * 2);                  // 2 MB
  if (ws_size < off) return;                          // total 168 MB
  bf16* Qb = QKVb;
  bf16* Kb = QKVb + XN;
  bf16* Vb = QKVb + 2*XN;
  bf16* Pb = Vb;   // alias: V region dead after transpose; P = 21 MB <= 32 MB
  bf16* Rb = xb;   // alias: x region dead after QKV projection

  // fp32 -> bf16
  cvt_kernel<<<dim3((unsigned)(XN/1024)), dim3(256), 0, stream>>>(x, xb, (int)XN);
  cvt4_kernel<<<dim3((unsigned)(WN/1024), 4), dim3(256), 0, stream>>>(
      Wq, Wk, Wv, Wo, Wcat, Wcat + WN, Wcat + 2*WN, Wob);

  // fused QKV projection: [16384,1024] @ [3072,1024]^T -> split Q/K/V buffers
  gemm_bt<<<dim3(MTOT/128, 3*DIMD/128), dim3(256), 0, stream>>>(
      xb, Wcat, QKVb, nullptr, nullptr, 3*DIMD, DIMD, 1);

  // V transpose for PV B-operand
  transpose_kernel<<<dim3(TSEQ/64, DIMD/64, NBATCH), dim3(256), 0, stream>>>(Vb, Vtb);

  // banded weighted scores (128x128 tiles, 5-subtile band)
  score_kernel<<<dim3(NST, TSEQ/128, NBATCH), dim3(256), 0, stream>>>(Qb, Kb, Pb, dlogit);

  // P @ V
  pv_kernel<<<dim3(DIMD/128, TSEQ/128, NBATCH), dim3(256), 0, stream>>>(Pb, Vtb, Rb);

  // output projection with out_scale, fp32 out
  gemm_bt<<<dim3(MTOT/128, DIMD/128), dim3(256), 0, stream>>>(
      Rb, Wob, nullptr, out, oscale, DIMD, DIMD, 0);
}

// Round 3
// 407.753 us; speedup vs baseline: 1.0190x; 1.0155x over previous
//
#include <hip/hip_runtime.h>
#include <cstdint>

#define TSEQ 4096
#define DIMD 1024
#define NBATCH 4
#define MTOT (NBATCH*TSEQ)   // 16384 rows total
#define NST 3                // band subtiles of 128 => min future coverage 256 (tail ~2e-7)
#define PW (NST*128)         // 384 stored band width

typedef __bf16 bf16;
typedef bf16 bf16x8 __attribute__((ext_vector_type(8)));
typedef bf16 bf16x4 __attribute__((ext_vector_type(4)));
typedef float f32x4 __attribute__((ext_vector_type(4)));
typedef float f32x16 __attribute__((ext_vector_type(16)));

__device__ __forceinline__ void gl2lds16(const void* g, void* l) {
  // async global->LDS, 16B per lane; LDS dest is wave-uniform base + lane*16
  __builtin_amdgcn_global_load_lds(
      (__attribute__((address_space(1))) void*)(g),
      (__attribute__((address_space(3))) void*)(l), 16, 0, 0);
}
__device__ __forceinline__ f32x4 mfma16(bf16x8 a, bf16x8 b, f32x4 c) {
  return __builtin_amdgcn_mfma_f32_16x16x32_bf16(a, b, c, 0, 0, 0);
}
__device__ __forceinline__ f32x16 mfma32(bf16x8 a, bf16x8 b, f32x16 c) {
  return __builtin_amdgcn_mfma_f32_32x32x16_bf16(a, b, c, 0, 0, 0);
}

// ---------------- fp32 -> bf16 convert ----------------
__global__ void cvt_kernel(const float* __restrict__ in, bf16* __restrict__ out, int n) {
  int i = (blockIdx.x * 256 + threadIdx.x) * 4;
  if (i >= n) return;
  float4 v = *(const float4*)(in + i);
  bf16x4 o = { (bf16)v.x, (bf16)v.y, (bf16)v.z, (bf16)v.w };
  *(bf16x4*)(out + i) = o;
}

// 4 sources in one dispatch (weights); blockIdx.y selects the pair.
__global__ void cvt4_kernel(const float* __restrict__ s0, const float* __restrict__ s1,
                            const float* __restrict__ s2, const float* __restrict__ s3,
                            bf16* __restrict__ d0, bf16* __restrict__ d1,
                            bf16* __restrict__ d2, bf16* __restrict__ d3) {
  const float* srcs[4] = {s0, s1, s2, s3};
  bf16*        dsts[4] = {d0, d1, d2, d3};
  const float* in = srcs[blockIdx.y];
  bf16* out = dsts[blockIdx.y];
  int i = (blockIdx.x * 256 + threadIdx.x) * 4;
  float4 v = *(const float4*)(in + i);
  bf16x4 o = { (bf16)v.x, (bf16)v.y, (bf16)v.z, (bf16)v.w };
  *(bf16x4*)(out + i) = o;
}

// ---------------- C = A @ B^T  (A[M,K], B[N,K] both row-major bf16) ----------------
// 128x128 tile, 4 waves 2x2, each wave 2x2 of 32x32x16 MFMAs per K-chunk of 32.
// 32x32 shape: half the MFMA issue slots of 16x16 at a 15% higher measured ceiling (m119).
// split!=0: output col>>10 selects Q/K/V buffer (fused QKV projection).
__global__ void gemm_bt(const bf16* __restrict__ A, const bf16* __restrict__ B,
                        bf16* __restrict__ Cb, float* __restrict__ Cf,
                        const float* __restrict__ scale_ptr, int N, int K, int split) {
  __shared__ bf16 As[128*32];
  __shared__ bf16 Bs[128*32];
  const int tid = threadIdx.x;
  const int wave = tid >> 6, lane = tid & 63;
  const int row0 = blockIdx.x * 128, col0 = blockIdx.y * 128;
  const int wr = wave >> 1, wc = wave & 1;
  f32x16 acc[2][2] = {};
  const int srow = wave*32 + (lane>>2);
  const int scol = (lane&3)*8;
  const bf16* gA = A + (size_t)(row0 + srow)*K + scol;
  const bf16* gB = B + (size_t)(col0 + srow)*K + scol;
  bf16* lA = As + (wave*32)*32;
  bf16* lB = Bs + (wave*32)*32;
  for (int k0 = 0; k0 < K; k0 += 32) {
    gl2lds16(gA,                lA);
    gl2lds16(gA + (size_t)16*K, lA + 16*32);
    gl2lds16(gB,                lB);
    gl2lds16(gB + (size_t)16*K, lB + 16*32);
    gA += 32; gB += 32;
    __syncthreads();
    bf16x8 af[2][2], bfr[2][2];
    #pragma unroll
    for (int mt = 0; mt < 2; ++mt)
      #pragma unroll
      for (int kc = 0; kc < 2; ++kc) {
        af[mt][kc]  = *(const bf16x8*)(As + (wr*64 + mt*32 + (lane&31))*32 + kc*16 + (lane>>5)*8);
        bfr[mt][kc] = *(const bf16x8*)(Bs + (wc*64 + mt*32 + (lane&31))*32 + kc*16 + (lane>>5)*8);
      }
    #pragma unroll
    for (int kc = 0; kc < 2; ++kc)
      #pragma unroll
      for (int mt = 0; mt < 2; ++mt)
        #pragma unroll
        for (int nt = 0; nt < 2; ++nt)
          acc[mt][nt] = mfma32(af[mt][kc], bfr[nt][kc], acc[mt][nt]);
    __syncthreads();
  }
  float sc = scale_ptr ? *scale_ptr : 1.0f;
  // C/D 32x32 layout (m74/m101): col=lane&31, row=(r&3)+8*(r>>2)+4*(lane>>5)
  #pragma unroll
  for (int mt = 0; mt < 2; ++mt)
    #pragma unroll
    for (int nt = 0; nt < 2; ++nt) {
      int col   = col0 + wc*64 + nt*32 + (lane & 31);
      int rbase = row0 + wr*64 + mt*32 + 4*(lane >> 5);
      #pragma unroll
      for (int r = 0; r < 16; ++r) {
        int row = rbase + (r & 3) + 8*(r >> 2);
        float v = acc[mt][nt][r] * sc;
        if (split) {
          size_t idx = ((size_t)(col >> 10) * MTOT + row) * 1024 + (col & 1023);
          Cb[idx] = (bf16)v;
        } else if (Cf) {
          Cf[(size_t)row*N + col] = v;
        } else {
          Cb[(size_t)row*N + col] = (bf16)v;
        }
      }
    }
}

// ---------------- V[b][T][D] -> Vt[b][D][T] ----------------
__global__ void transpose_kernel(const bf16* __restrict__ V, bf16* __restrict__ Vt) {
  __shared__ bf16 tile[64][72];   // +8 pad keeps 16B alignment, breaks bank stride
  int b = blockIdx.z;
  int t0 = blockIdx.x * 64, c0 = blockIdx.y * 64;
  int tid = threadIdx.x;
  int r = tid >> 2, cb = (tid & 3) * 16;
  const bf16* src = V + ((size_t)b*TSEQ + t0 + r)*DIMD + c0 + cb;
  *(bf16x8*)&tile[r][cb]     = *(const bf16x8*)src;
  *(bf16x8*)&tile[r][cb + 8] = *(const bf16x8*)(src + 8);
  __syncthreads();
  int cr = tid >> 2, tb = (tid & 3) * 16;
  bf16x8 o0, o1;
  #pragma unroll
  for (int j = 0; j < 8; ++j) { o0[j] = tile[tb+j][cr]; o1[j] = tile[tb+8+j][cr]; }
  bf16* dst = Vt + ((size_t)b*DIMD + c0 + cr)*TSEQ + t0 + tb;
  *(bf16x8*)dst       = o0;
  *(bf16x8*)(dst + 8) = o1;
}

// ---------------- banded weighted scores, 128x128 tiles ----------------
// P[b][qt][row 0..127][j 0..PW-1], j = s - qt*128. One block per (st, qt, b).
__global__ void score_kernel(const bf16* __restrict__ Q, const bf16* __restrict__ Km,
                             bf16* __restrict__ P, const float* __restrict__ dlogit) {
  __shared__ bf16 Qs[128*32];
  __shared__ bf16 Ks[128*32];
  const int st = blockIdx.x, qt = blockIdx.y, b = blockIdx.z;
  const int i0 = qt*128, s0 = i0 + st*128;
  const int tid = threadIdx.x, wave = tid>>6, lane = tid&63;
  const int wr = wave>>1, wc = wave&1;
  bf16* Pp = P + ((size_t)b*(TSEQ/128) + qt)*128*PW;
  if (s0 >= TSEQ) {            // fully out-of-range tile: write zeros (pv reads full band)
    int row = tid >> 1, cb = (tid & 1)*64;
    bf16x8 z = {};
    #pragma unroll
    for (int v = 0; v < 8; ++v)
      *(bf16x8*)(Pp + (size_t)row*PW + st*128 + cb + v*8) = z;
    return;
  }
  f32x4 acc[4][4] = {};
  const int srow = wave*32 + (lane>>2);
  const int scol = (lane&3)*8;
  const bf16* gq = Q + ((size_t)b*TSEQ + i0 + srow)*DIMD + scol;
  int sr1 = s0 + srow;      if (sr1 > TSEQ-1) sr1 = TSEQ-1;   // clamp OOB rows; w=0 masks
  int sr2 = s0 + srow + 16; if (sr2 > TSEQ-1) sr2 = TSEQ-1;
  const bf16* gk1 = Km + ((size_t)b*TSEQ + sr1)*DIMD + scol;
  const bf16* gk2 = Km + ((size_t)b*TSEQ + sr2)*DIMD + scol;
  bf16* lq = Qs + (wave*32)*32;
  bf16* lk = Ks + (wave*32)*32;
  for (int k0 = 0; k0 < DIMD; k0 += 32) {
    gl2lds16(gq,            lq);
    gl2lds16(gq + 16*DIMD,  lq + 16*32);
    gl2lds16(gk1,           lk);
    gl2lds16(gk2,           lk + 16*32);
    gq += 32; gk1 += 32; gk2 += 32;
    __syncthreads();
    bf16x8 af[4], bfr[4];
    #pragma unroll
    for (int i = 0; i < 4; ++i) {
      af[i]  = *(const bf16x8*)(Qs + (wr*64 + i*16 + (lane&15))*32 + (lane>>4)*8);
      bfr[i] = *(const bf16x8*)(Ks + (wc*64 + i*16 + (lane&15))*32 + (lane>>4)*8);
    }
    #pragma unroll
    for (int i = 0; i < 4; ++i)
      #pragma unroll
      for (int j = 0; j < 4; ++j)
        acc[i][j] = mfma16(af[i], bfr[j], acc[i][j]);
    __syncthreads();
  }
  float decay = 1.0f / (1.0f + expf(-*dlogit));
  float l2d = log2f(decay);
  #pragma unroll
  for (int i = 0; i < 4; ++i) {
    #pragma unroll
    for (int j = 0; j < 4; ++j) {
      int col = wc*64 + j*16 + (lane&15);
      int s = s0 + col;
      #pragma unroll
      for (int r = 0; r < 4; ++r) {
        int row = wr*64 + i*16 + (lane>>4)*4 + r;
        int t = i0 + row;
        float w = (s > t && s < TSEQ) ? exp2f((float)(s - t - 1) * l2d) : 0.0f;
        Pp[(size_t)row*PW + st*128 + col] = (bf16)(acc[i][j][r] * 0.03125f * w);
      }
    }
  }
}

// ---------------- R[128x128 tile] = P_band @ V  (B operand from Vt) ----------------
__global__ void pv_kernel(const bf16* __restrict__ P, const bf16* __restrict__ Vt,
                          bf16* __restrict__ R) {
  __shared__ bf16 Ps[128*32];
  __shared__ bf16 Vs[128*32];
  const int cb = blockIdx.x, qt = blockIdx.y, b = blockIdx.z;
  const int i0 = qt*128, c0 = cb*128;
  const int tid = threadIdx.x, wave = tid>>6, lane = tid&63;
  const int wr = wave>>1, wc = wave&1;
  f32x4 acc[4][4] = {};
  const bf16* Pp = P + ((size_t)b*(TSEQ/128) + qt)*128*PW;
  const int srow = wave*32 + (lane>>2);
  const int scol = (lane&3)*8;
  const bf16* gp = Pp + (size_t)srow*PW + scol;
  bf16* lp = Ps + (wave*32)*32;
  bf16* lv = Vs + (wave*32)*32;
  const bf16* vbase1 = Vt + ((size_t)b*DIMD + c0 + srow)*TSEQ;
  const bf16* vbase2 = vbase1 + (size_t)16*TSEQ;
  for (int k0 = 0; k0 < PW; k0 += 32) {
    gl2lds16(gp,           lp);
    gl2lds16(gp + 16*PW,   lp + 16*32);
    int s = i0 + k0 + scol;
    if (s >= TSEQ) s = 0;              // OOB k: P is 0 there, any valid addr works
    gl2lds16(vbase1 + s,   lv);
    gl2lds16(vbase2 + s,   lv + 16*32);
    gp += 32;
    __syncthreads();
    bf16x8 af[4], bfr[4];
    #pragma unroll
    for (int i = 0; i < 4; ++i) {
      af[i]  = *(const bf16x8*)(Ps + (wr*64 + i*16 + (lane&15))*32 + (lane>>4)*8);
      bfr[i] = *(const bf16x8*)(Vs + (wc*64 + i*16 + (lane&15))*32 + (lane>>4)*8);
    }
    #pragma unroll
    for (int i = 0; i < 4; ++i)
      #pragma unroll
      for (int j = 0; j < 4; ++j)
        acc[i][j] = mfma16(af[i], bfr[j], acc[i][j]);
    __syncthreads();
  }
  #pragma unroll
  for (int i = 0; i < 4; ++i)
    #pragma unroll
    for (int j = 0; j < 4; ++j) {
      int col  = c0 + wc*64 + j*16 + (lane&15);
      int rowb = i0 + wr*64 + i*16 + (lane>>4)*4;
      #pragma unroll
      for (int r = 0; r < 4; ++r)
        R[((size_t)b*TSEQ + rowb + r)*DIMD + col] = (bf16)acc[i][j][r];
    }
}

extern "C" void kernel_launch(void* const* d_in, const int* in_sizes, int n_in,
                              void* d_out, int out_size, void* d_ws, size_t ws_size,
                              hipStream_t stream) {
  const float* x      = (const float*)d_in[0];
  const float* Wq     = (const float*)d_in[1];
  const float* Wk     = (const float*)d_in[2];
  const float* Wv     = (const float*)d_in[3];
  const float* Wo     = (const float*)d_in[4];
  const float* dlogit = (const float*)d_in[5];
  const float* oscale = (const float*)d_in[6];
  float* out = (float*)d_out;

  char* ws = (char*)d_ws;
  size_t off = 0;
  auto alloc = [&](size_t bytes) -> void* {
    void* p = ws + off; off += (bytes + 255) & ~(size_t)255; return p;
  };
  const size_t XN = (size_t)MTOT * DIMD;              // 16,777,216 elements
  const size_t WN = (size_t)DIMD * DIMD;
  bf16* xb   = (bf16*)alloc(XN * 2);                  // 32 MB
  bf16* QKVb = (bf16*)alloc(3 * XN * 2);              // 96 MB: Q | K | V
  bf16* Vtb  = (bf16*)alloc(XN * 2);                  // 32 MB
  bf16* Wcat = (bf16*)alloc(3 * WN * 2);              // 6 MB: Wq | Wk | Wv rows
  bf16* Wob  = (bf16*)alloc(WN * 2);                  // 2 MB
  if (ws_size < off) return;                          // total 168 MB
  bf16* Qb = QKVb;
  bf16* Kb = QKVb + XN;
  bf16* Vb = QKVb + 2*XN;
  bf16* Pb = Vb;   // alias: V region dead after transpose; P = 12.6 MB <= 32 MB
  bf16* Rb = xb;   // alias: x region dead after QKV projection

  // fp32 -> bf16
  cvt_kernel<<<dim3((unsigned)(XN/1024)), dim3(256), 0, stream>>>(x, xb, (int)XN);
  cvt4_kernel<<<dim3((unsigned)(WN/1024), 4), dim3(256), 0, stream>>>(
      Wq, Wk, Wv, Wo, Wcat, Wcat + WN, Wcat + 2*WN, Wob);

  // fused QKV projection: [16384,1024] @ [3072,1024]^T -> split Q/K/V buffers
  gemm_bt<<<dim3(MTOT/128, 3*DIMD/128), dim3(256), 0, stream>>>(
      xb, Wcat, QKVb, nullptr, nullptr, 3*DIMD, DIMD, 1);

  // V transpose for PV B-operand
  transpose_kernel<<<dim3(TSEQ/64, DIMD/64, NBATCH), dim3(256), 0, stream>>>(Vb, Vtb);

  // banded weighted scores (128x128 tiles, 3-subtile band)
  score_kernel<<<dim3(NST, TSEQ/128, NBATCH), dim3(256), 0, stream>>>(Qb, Kb, Pb, dlogit);

  // P @ V
  pv_kernel<<<dim3(DIMD/128, TSEQ/128, NBATCH), dim3(256), 0, stream>>>(Pb, Vtb, Rb);

  // output projection with out_scale, fp32 out
  gemm_bt<<<dim3(MTOT/128, DIMD/128), dim3(256), 0, stream>>>(
      Rb, Wob, nullptr, out, oscale, DIMD, DIMD, 0);
}